// Round 7
// baseline (298.115 us; speedup 1.0000x reference)
//
#include <hip/hip_runtime.h>
#include <hip/hip_bf16.h>

// Problem constants
#define NB   64
#define NCDD 5
#define NHIS 100
#define ND   256
#define NK   10
#define TLD  23040          // T*L*D = 30*3*256
#define THRESH 0.1f
#define NEG_INF (-3.402823466e38f)
#define NROWS_HIS 6400      // 64*100
#define NROWS_CDD 320       // 64*5

typedef float f32x4 __attribute__((ext_vector_type(4)));

// ---------------------------------------------------------------------------
// Kernel 1: projection + L2-norm, 16 rows/block (420 blocks).
// W staged in LDS per 32-wide K-tile, TRANSPOSED (wt[kk][d]):
//   - global load: wave reads 8 W-rows x 128B chunks -> minimal cache lines
//   - LDS read wt[kk][tid]: consecutive lanes -> consecutive addr, no conflict
// X rows are lane-uniform -> scalar pipe. FMA floor ~5.5 us.
// ---------------------------------------------------------------------------
__global__ __launch_bounds__(256) void proj_norm_all(
    const float* __restrict__ his_repr,
    const float* __restrict__ cdd_repr,
    const float* __restrict__ W,
    const float* __restrict__ bvec,
    float* __restrict__ Yall)
{
    __shared__ float wt[32][257];      // [kk][d], padded: write-side ~2-way max
    __shared__ float red[4][16];
    const int r0  = blockIdx.x * 16;
    const int tid = threadIdx.x;

    const float* __restrict__ X = (r0 < NROWS_HIS)
        ? (his_repr + (size_t)r0 * ND)
        : (cdd_repr + (size_t)(r0 - NROWS_HIS) * ND);

    const float bias = bvec[tid];
    float acc[16];
#pragma unroll
    for (int r = 0; r < 16; ++r) acc[r] = bias;

    for (int kt = 0; kt < 8; ++kt) {
        const int k0 = kt * 32;
        // Stage W tile [d=0..255][k0..k0+31] into wt[kk][d] (transposed)
#pragma unroll
        for (int j = 0; j < 8; ++j) {
            const int f   = tid + j * 256;     // 0..2047 float4-slots
            const int d   = f >> 3;            // 0..255
            const int kk4 = (f & 7) << 2;      // 0,4,..,28
            const float4 w4 = *(const float4*)(W + (size_t)d * ND + k0 + kk4);
            wt[kk4 + 0][d] = w4.x;
            wt[kk4 + 1][d] = w4.y;
            wt[kk4 + 2][d] = w4.z;
            wt[kk4 + 3][d] = w4.w;
        }
        __syncthreads();

#pragma unroll
        for (int j = 0; j < 8; ++j) {
            const float w0 = wt[4 * j + 0][tid];
            const float w1 = wt[4 * j + 1][tid];
            const float w2 = wt[4 * j + 2][tid];
            const float w3 = wt[4 * j + 3][tid];
#pragma unroll
            for (int r = 0; r < 16; ++r) {
                const float4 x4 = *(const float4*)(X + (size_t)r * ND + k0 + 4 * j); // uniform
                acc[r] += x4.x * w0 + x4.y * w1 + x4.z * w2 + x4.w * w3;
            }
        }
        __syncthreads();
    }

    const int wave = tid >> 6, lane = tid & 63;
#pragma unroll
    for (int r = 0; r < 16; ++r) {
        float v = acc[r] * acc[r];
        for (int off = 32; off; off >>= 1) v += __shfl_xor(v, off);
        if (lane == 0) red[wave][r] = v;
    }
    __syncthreads();

#pragma unroll
    for (int r = 0; r < 16; ++r) {
        const float s = red[0][r] + red[1][r] + red[2][r] + red[3][r];
        const float scale = 1.0f / fmaxf(sqrtf(s), 1e-12f);
        Yall[(size_t)(r0 + r) * ND + tid] = acc[r] * scale;
    }
}

// ---------------------------------------------------------------------------
// Kernel 2: one block per b (512 thr, 8 waves). Dot phase: wave-cooperative —
// the wave loads his_p row h as 64 lanes x float4 (fully coalesced, the row
// IS the wave's 1KB transaction), dot4 + 6-step butterfly reduce. 500 (c,h)
// tasks round-robin over 8 waves. cdd vectors read per-task from LDS
// (consecutive lanes -> conflict-free b128). Top-k: 5 waves, one c each,
// lax.top_k semantics (descending, lowest index on ties).
// ---------------------------------------------------------------------------
__global__ __launch_bounds__(512) void attn_topk_kernel(
    const float* __restrict__ cdd_p,
    const float* __restrict__ his_p,
    float* __restrict__ out_idx_f,
    int* __restrict__ ws_idx,
    float* __restrict__ ws_w)
{
    __shared__ f32x4 cdds[NCDD * 64];        // 5 KB
    __shared__ float attn_s[NCDD][128];      // padded
    const int b   = blockIdx.x;
    const int tid = threadIdx.x;
    const int wave = tid >> 6, lane = tid & 63;

    for (int i = tid; i < NCDD * 64; i += 512)
        cdds[i] = ((const f32x4*)(cdd_p + (size_t)b * NCDD * ND))[i];
    __syncthreads();

    for (int idx = wave; idx < NCDD * NHIS; idx += 8) {
        const int c = idx / NHIS, h = idx - c * NHIS;
        const f32x4 cv = cdds[c * 64 + lane];
        const f32x4 hv =
            ((const f32x4*)(his_p + ((size_t)b * NHIS + h) * ND))[lane];
        float v = cv[0] * hv[0] + cv[1] * hv[1] + cv[2] * hv[2] + cv[3] * hv[3];
#pragma unroll
        for (int off = 32; off; off >>= 1) v += __shfl_xor(v, off);
        if (lane == 0) attn_s[c][h] = v;
    }
    __syncthreads();

    if (wave < NCDD) {
        const int c = wave;
        float v0 = attn_s[c][lane];
        float v1 = (lane + 64 < NHIS) ? attn_s[c][lane + 64] : NEG_INF;
#pragma unroll
        for (int k = 0; k < NK; ++k) {
            float lv; int li;
            if (v1 > v0) { lv = v1; li = lane + 64; }
            else         { lv = v0; li = lane; }            // tie -> lower idx
            for (int off = 1; off < 64; off <<= 1) {
                const float ov = __shfl_xor(lv, off);
                const int   oi = __shfl_xor(li, off);
                if (ov > lv || (ov == lv && oi < li)) { lv = ov; li = oi; }
            }
            if (lane == 0) {
                const float w = (lv < THRESH) ? 0.0f : lv;
                const int g = (b * NCDD + c) * NK + k;
                ws_idx[g] = li;
                ws_w[g]   = w;
                out_idx_f[g] = (float)li;
            }
            if (li == lane)            v0 = NEG_INF;
            else if (li == lane + 64)  v1 = NEG_INF;
        }
    }
}

// ---------------------------------------------------------------------------
// Kernel 3: gather + scale — BYTE-IDENTICAL to R4/R5/R6 (calibrated control,
// G ~= 106 us measured by the R6 double-launch).
// ---------------------------------------------------------------------------
__global__ __launch_bounds__(256) void gather_kernel(
    const float* __restrict__ his_emb,
    const int* __restrict__ ws_idx,
    const float* __restrict__ ws_w,
    float* __restrict__ out)
{
    const int orig = blockIdx.x;
    const int g = (orig & 7) * 400 + (orig >> 3);   // XCD-chunked (bijective)
    const int b = g / (NCDD * NK);
    const int tid = threadIdx.x;
    const float w = ws_w[g];

    f32x4* __restrict__ dst = (f32x4*)(out + (size_t)g * TLD);

    if (w == 0.0f) {
        const f32x4 z = {0.f, 0.f, 0.f, 0.f};
#pragma unroll
        for (int it = 0; it < 22; ++it) dst[tid + it * 256] = z;
        if (tid < 128) dst[22 * 256 + tid] = z;
        return;
    }

    const int idx = ws_idx[g];
    const f32x4* __restrict__ src =
        (const f32x4*)(his_emb + ((size_t)b * NHIS + idx) * TLD);

    f32x4 v[8];
#pragma unroll
    for (int j = 0; j < 8; ++j) v[j] = src[tid + j * 256];
#pragma unroll
    for (int j = 0; j < 8; ++j) dst[tid + j * 256] = v[j] * w;
#pragma unroll
    for (int j = 0; j < 8; ++j) v[j] = src[tid + (8 + j) * 256];
#pragma unroll
    for (int j = 0; j < 8; ++j) dst[tid + (8 + j) * 256] = v[j] * w;
#pragma unroll
    for (int j = 0; j < 6; ++j) v[j] = src[tid + (16 + j) * 256];
#pragma unroll
    for (int j = 0; j < 6; ++j) dst[tid + (16 + j) * 256] = v[j] * w;
    if (tid < 128) {
        const int i = 22 * 256 + tid;
        f32x4 t = src[i];
        dst[i] = t * w;
    }
}

// ---------------------------------------------------------------------------
extern "C" void kernel_launch(void* const* d_in, const int* in_sizes, int n_in,
                              void* d_out, int out_size, void* d_ws, size_t ws_size,
                              hipStream_t stream)
{
    const float* cdd_repr = (const float*)d_in[0];   // (64,5,256)
    const float* his_repr = (const float*)d_in[1];   // (64,100,256)
    const float* his_emb  = (const float*)d_in[2];   // (64,100,30,3,256)
    const float* W_sel    = (const float*)d_in[3];   // (256,256)
    const float* b_sel    = (const float*)d_in[4];   // (256,)
    float* out = (float*)d_out;

    // Workspace layout
    char* ws = (char*)d_ws;
    float* Yall  = (float*)ws;                       // 6720 rows * 256 * 4
    float* his_p = Yall;                             // rows [0, 6400)
    float* cdd_p = Yall + (size_t)NROWS_HIS * ND;    // rows [6400, 6720)
    int*   idx_i = (int*)  (ws + 6881280);           // 3200*4
    float* w_w   = (float*)(ws + 6894080);           // 3200*4

    // Output: his_activated [73,728,000] then idx [3200] (as float values)
    float* out_idx_f = out + (size_t)NB * NCDD * NK * TLD;

    proj_norm_all<<<(NROWS_HIS + NROWS_CDD) / 16, 256, 0, stream>>>(
        his_repr, cdd_repr, W_sel, b_sel, Yall);
    attn_topk_kernel<<<NB, 512, 0, stream>>>(cdd_p, his_p,
                                             out_idx_f, idx_i, w_w);
    gather_kernel<<<NB * NCDD * NK, 256, 0, stream>>>(his_emb, idx_i, w_w, out);
}

// Round 8
// 165.645 us; speedup vs baseline: 1.7997x; 1.7997x over previous
//
#include <hip/hip_runtime.h>
#include <hip/hip_bf16.h>

// Problem constants
#define NB   64
#define NCDD 5
#define NHIS 100
#define ND   256
#define NK   10
#define TLD  23040          // T*L*D = 30*3*256
#define THRESH 0.1f
#define NEG_INF (-3.402823466e38f)
#define NROWS_HIS 6400      // 64*100
#define NROWS_CDD 320       // 64*5

typedef float f32x4 __attribute__((ext_vector_type(4)));

// ---------------------------------------------------------------------------
// Kernel 1: projection + L2-norm, 8 rows/block (840 blocks).
// 4-lane cooperative columns, ALL loads in the vmcnt domain (no LDS in the
// hot loop, no barriers):
//   sub = tid&3 owns k-slice {sub*4 + 16*i}, grp = tid>>2 owns column base.
//   W-load instruction: 16 groups x 64B contiguous -> ~16 lines/wave
//   (vs 64 single-line touches in the R5 per-thread-row version).
//   X-load instruction: 4 distinct 16B addrs shared by 16 groups -> 1 line.
// Partial dots combine via 2-step shfl_xor butterfly (width 4).
// ---------------------------------------------------------------------------
__global__ __launch_bounds__(256) void proj_norm_all(
    const float* __restrict__ his_repr,
    const float* __restrict__ cdd_repr,
    const float* __restrict__ W,
    const float* __restrict__ bvec,
    float* __restrict__ Yall)
{
    __shared__ float red[4][8];
    const int r0  = blockIdx.x * 8;
    const int tid = threadIdx.x;
    const int sub = tid & 3;           // k-slice within a 4-lane group
    const int grp = tid >> 2;          // 0..63: column group (block-wide)
    const int wave = tid >> 6, lane = tid & 63;

    const float* __restrict__ X = (r0 < NROWS_HIS)
        ? (his_repr + (size_t)r0 * ND)
        : (cdd_repr + (size_t)(r0 - NROWS_HIS) * ND);

    // acc[p][r]: partial dot for output col d = p*64+grp, input row r
    float acc[4][8];
#pragma unroll
    for (int p = 0; p < 4; ++p)
#pragma unroll
        for (int r = 0; r < 8; ++r) acc[p][r] = 0.f;

#pragma unroll 4
    for (int i = 0; i < 16; ++i) {
        const int kb = sub * 4 + 16 * i;
        float4 x4[8];
#pragma unroll
        for (int r = 0; r < 8; ++r)
            x4[r] = *(const float4*)(X + (size_t)r * ND + kb);
#pragma unroll
        for (int p = 0; p < 4; ++p) {
            const int d = p * 64 + grp;
            const float4 w4 = *(const float4*)(W + (size_t)d * ND + kb);
#pragma unroll
            for (int r = 0; r < 8; ++r)
                acc[p][r] += w4.x * x4[r].x + w4.y * x4[r].y
                           + w4.z * x4[r].z + w4.w * x4[r].w;
        }
    }

    // Butterfly across the 4 sub-lanes: all lanes end with the full dot.
#pragma unroll
    for (int p = 0; p < 4; ++p)
#pragma unroll
        for (int r = 0; r < 8; ++r) {
            float v = acc[p][r];
            v += __shfl_xor(v, 1);
            v += __shfl_xor(v, 2);
            acc[p][r] = v;
        }

    // y[p][r] = dot + bias(d);  d = p*64+grp
    float bias[4];
#pragma unroll
    for (int p = 0; p < 4; ++p) bias[p] = bvec[p * 64 + grp];

    // Row sum-of-squares. Every lane holds 4 cols (x4 duplicated across sub),
    // so a full-wave butterfly gives 4x the true partial sum; divide later.
    float ss[8];
#pragma unroll
    for (int r = 0; r < 8; ++r) {
        float t = 0.f;
#pragma unroll
        for (int p = 0; p < 4; ++p) {
            const float y = acc[p][r] + bias[p];
            acc[p][r] = y;
            t += y * y;
        }
        for (int off = 32; off; off >>= 1) t += __shfl_xor(t, off);
        ss[r] = t;
    }
    if (lane == 0) {
#pragma unroll
        for (int r = 0; r < 8; ++r) red[wave][r] = ss[r];
    }
    __syncthreads();

#pragma unroll
    for (int r = 0; r < 8; ++r) {
        const float s = 0.25f * (red[0][r] + red[1][r] + red[2][r] + red[3][r]);
        const float scale = 1.0f / fmaxf(sqrtf(s), 1e-12f);
        if (sub == 0) {
#pragma unroll
            for (int p = 0; p < 4; ++p)
                Yall[(size_t)(r0 + r) * ND + p * 64 + grp] = acc[p][r] * scale;
        }
    }
}

// ---------------------------------------------------------------------------
// Kernel 2: one block per b (512 thr). 4-lane-group cooperative dots, all
// VMEM: group handles task (c,h); lane sub dots k-slice {sub*4+16*i}; 2-shfl
// butterfly; sub==0 writes attn_s. 128 groups/block x 4 iters covers 500.
// Then 5 waves run the exact top-10 (lax.top_k: descending, lowest idx ties).
// ---------------------------------------------------------------------------
__global__ __launch_bounds__(512) void attn_topk_kernel(
    const float* __restrict__ cdd_p,
    const float* __restrict__ his_p,
    float* __restrict__ out_idx_f,
    int* __restrict__ ws_idx,
    float* __restrict__ ws_w)
{
    __shared__ float attn_s[NCDD][128];      // padded
    const int b   = blockIdx.x;
    const int tid = threadIdx.x;
    const int sub = tid & 3, grp = tid >> 2;   // grp 0..127
    const int wave = tid >> 6, lane = tid & 63;

    const float* __restrict__ cbase = cdd_p + (size_t)b * NCDD * ND;
    const float* __restrict__ hbase = his_p + (size_t)b * NHIS * ND;

#pragma unroll
    for (int it = 0; it < 4; ++it) {
        const int task = it * 128 + grp;
        if (task < NCDD * NHIS) {
            const int c = task / NHIS, h = task - c * NHIS;
            const float* __restrict__ crow = cbase + (size_t)c * ND;
            const float* __restrict__ hrow = hbase + (size_t)h * ND;
            float a = 0.f;
#pragma unroll
            for (int i = 0; i < 16; ++i) {
                const int kb = sub * 4 + 16 * i;
                const float4 cv = *(const float4*)(crow + kb);
                const float4 hv = *(const float4*)(hrow + kb);
                a += cv.x * hv.x + cv.y * hv.y + cv.z * hv.z + cv.w * hv.w;
            }
            a += __shfl_xor(a, 1);
            a += __shfl_xor(a, 2);
            if (sub == 0) attn_s[c][h] = a;
        }
    }
    __syncthreads();

    if (wave < NCDD) {
        const int c = wave;
        float v0 = attn_s[c][lane];
        float v1 = (lane + 64 < NHIS) ? attn_s[c][lane + 64] : NEG_INF;
#pragma unroll
        for (int k = 0; k < NK; ++k) {
            float lv; int li;
            if (v1 > v0) { lv = v1; li = lane + 64; }
            else         { lv = v0; li = lane; }            // tie -> lower idx
            for (int off = 1; off < 64; off <<= 1) {
                const float ov = __shfl_xor(lv, off);
                const int   oi = __shfl_xor(li, off);
                if (ov > lv || (ov == lv && oi < li)) { lv = ov; li = oi; }
            }
            if (lane == 0) {
                const float w = (lv < THRESH) ? 0.0f : lv;
                const int g = (b * NCDD + c) * NK + k;
                ws_idx[g] = li;
                ws_w[g]   = w;
                out_idx_f[g] = (float)li;
            }
            if (li == lane)            v0 = NEG_INF;
            else if (li == lane + 64)  v1 = NEG_INF;
        }
    }
}

// ---------------------------------------------------------------------------
// Kernel 3: gather + scale — BYTE-IDENTICAL to R4/R5/R6 (calibrated control,
// G ~= 106 us from the R6 double-launch).
// ---------------------------------------------------------------------------
__global__ __launch_bounds__(256) void gather_kernel(
    const float* __restrict__ his_emb,
    const int* __restrict__ ws_idx,
    const float* __restrict__ ws_w,
    float* __restrict__ out)
{
    const int orig = blockIdx.x;
    const int g = (orig & 7) * 400 + (orig >> 3);   // XCD-chunked (bijective)
    const int b = g / (NCDD * NK);
    const int tid = threadIdx.x;
    const float w = ws_w[g];

    f32x4* __restrict__ dst = (f32x4*)(out + (size_t)g * TLD);

    if (w == 0.0f) {
        const f32x4 z = {0.f, 0.f, 0.f, 0.f};
#pragma unroll
        for (int it = 0; it < 22; ++it) dst[tid + it * 256] = z;
        if (tid < 128) dst[22 * 256 + tid] = z;
        return;
    }

    const int idx = ws_idx[g];
    const f32x4* __restrict__ src =
        (const f32x4*)(his_emb + ((size_t)b * NHIS + idx) * TLD);

    f32x4 v[8];
#pragma unroll
    for (int j = 0; j < 8; ++j) v[j] = src[tid + j * 256];
#pragma unroll
    for (int j = 0; j < 8; ++j) dst[tid + j * 256] = v[j] * w;
#pragma unroll
    for (int j = 0; j < 8; ++j) v[j] = src[tid + (8 + j) * 256];
#pragma unroll
    for (int j = 0; j < 8; ++j) dst[tid + (8 + j) * 256] = v[j] * w;
#pragma unroll
    for (int j = 0; j < 6; ++j) v[j] = src[tid + (16 + j) * 256];
#pragma unroll
    for (int j = 0; j < 6; ++j) dst[tid + (16 + j) * 256] = v[j] * w;
    if (tid < 128) {
        const int i = 22 * 256 + tid;
        f32x4 t = src[i];
        dst[i] = t * w;
    }
}

// ---------------------------------------------------------------------------
extern "C" void kernel_launch(void* const* d_in, const int* in_sizes, int n_in,
                              void* d_out, int out_size, void* d_ws, size_t ws_size,
                              hipStream_t stream)
{
    const float* cdd_repr = (const float*)d_in[0];   // (64,5,256)
    const float* his_repr = (const float*)d_in[1];   // (64,100,256)
    const float* his_emb  = (const float*)d_in[2];   // (64,100,30,3,256)
    const float* W_sel    = (const float*)d_in[3];   // (256,256)
    const float* b_sel    = (const float*)d_in[4];   // (256,)
    float* out = (float*)d_out;

    // Workspace layout
    char* ws = (char*)d_ws;
    float* Yall  = (float*)ws;                       // 6720 rows * 256 * 4
    float* his_p = Yall;                             // rows [0, 6400)
    float* cdd_p = Yall + (size_t)NROWS_HIS * ND;    // rows [6400, 6720)
    int*   idx_i = (int*)  (ws + 6881280);           // 3200*4
    float* w_w   = (float*)(ws + 6894080);           // 3200*4

    // Output: his_activated [73,728,000] then idx [3200] (as float values)
    float* out_idx_f = out + (size_t)NB * NCDD * NK * TLD;

    proj_norm_all<<<(NROWS_HIS + NROWS_CDD) / 8, 256, 0, stream>>>(
        his_repr, cdd_repr, W_sel, b_sel, Yall);
    attn_topk_kernel<<<NB, 512, 0, stream>>>(cdd_p, his_p,
                                             out_idx_f, idx_i, w_w);
    gather_kernel<<<NB * NCDD * NK, 256, 0, stream>>>(his_emb, idx_i, w_w, out);
}

// Round 9
// 162.311 us; speedup vs baseline: 1.8367x; 1.0205x over previous
//
#include <hip/hip_runtime.h>
#include <hip/hip_bf16.h>

// Problem constants
#define NB   64
#define NCDD 5
#define NHIS 100
#define ND   256
#define NK   10
#define TLD  23040          // T*L*D = 30*3*256
#define THRESH 0.1f
#define NEG_INF (-3.402823466e38f)
#define NROWS_HIS 6400      // 64*100
#define NROWS_CDD 320       // 64*5

typedef float f32x4 __attribute__((ext_vector_type(4)));

// ---------------------------------------------------------------------------
// Kernel 1: BYTE-IDENTICAL to R8 (control).
// ---------------------------------------------------------------------------
__global__ __launch_bounds__(256) void proj_norm_all(
    const float* __restrict__ his_repr,
    const float* __restrict__ cdd_repr,
    const float* __restrict__ W,
    const float* __restrict__ bvec,
    float* __restrict__ Yall)
{
    __shared__ float red[4][8];
    const int r0  = blockIdx.x * 8;
    const int tid = threadIdx.x;
    const int sub = tid & 3;           // k-slice within a 4-lane group
    const int grp = tid >> 2;          // 0..63: column group (block-wide)
    const int wave = tid >> 6, lane = tid & 63;

    const float* __restrict__ X = (r0 < NROWS_HIS)
        ? (his_repr + (size_t)r0 * ND)
        : (cdd_repr + (size_t)(r0 - NROWS_HIS) * ND);

    float acc[4][8];
#pragma unroll
    for (int p = 0; p < 4; ++p)
#pragma unroll
        for (int r = 0; r < 8; ++r) acc[p][r] = 0.f;

#pragma unroll 4
    for (int i = 0; i < 16; ++i) {
        const int kb = sub * 4 + 16 * i;
        float4 x4[8];
#pragma unroll
        for (int r = 0; r < 8; ++r)
            x4[r] = *(const float4*)(X + (size_t)r * ND + kb);
#pragma unroll
        for (int p = 0; p < 4; ++p) {
            const int d = p * 64 + grp;
            const float4 w4 = *(const float4*)(W + (size_t)d * ND + kb);
#pragma unroll
            for (int r = 0; r < 8; ++r)
                acc[p][r] += w4.x * x4[r].x + w4.y * x4[r].y
                           + w4.z * x4[r].z + w4.w * x4[r].w;
        }
    }

#pragma unroll
    for (int p = 0; p < 4; ++p)
#pragma unroll
        for (int r = 0; r < 8; ++r) {
            float v = acc[p][r];
            v += __shfl_xor(v, 1);
            v += __shfl_xor(v, 2);
            acc[p][r] = v;
        }

    float bias[4];
#pragma unroll
    for (int p = 0; p < 4; ++p) bias[p] = bvec[p * 64 + grp];

    float ss[8];
#pragma unroll
    for (int r = 0; r < 8; ++r) {
        float t = 0.f;
#pragma unroll
        for (int p = 0; p < 4; ++p) {
            const float y = acc[p][r] + bias[p];
            acc[p][r] = y;
            t += y * y;
        }
        for (int off = 32; off; off >>= 1) t += __shfl_xor(t, off);
        ss[r] = t;
    }
    if (lane == 0) {
#pragma unroll
        for (int r = 0; r < 8; ++r) red[wave][r] = ss[r];
    }
    __syncthreads();

#pragma unroll
    for (int r = 0; r < 8; ++r) {
        const float s = 0.25f * (red[0][r] + red[1][r] + red[2][r] + red[3][r]);
        const float scale = 1.0f / fmaxf(sqrtf(s), 1e-12f);
        if (sub == 0) {
#pragma unroll
            for (int p = 0; p < 4; ++p)
                Yall[(size_t)(r0 + r) * ND + p * 64 + grp] = acc[p][r] * scale;
        }
    }
}

// ---------------------------------------------------------------------------
// Kernel 2: BYTE-IDENTICAL to R8 (control).
// ---------------------------------------------------------------------------
__global__ __launch_bounds__(512) void attn_topk_kernel(
    const float* __restrict__ cdd_p,
    const float* __restrict__ his_p,
    float* __restrict__ out_idx_f,
    int* __restrict__ ws_idx,
    float* __restrict__ ws_w)
{
    __shared__ float attn_s[NCDD][128];      // padded
    const int b   = blockIdx.x;
    const int tid = threadIdx.x;
    const int sub = tid & 3, grp = tid >> 2;   // grp 0..127
    const int wave = tid >> 6, lane = tid & 63;

    const float* __restrict__ cbase = cdd_p + (size_t)b * NCDD * ND;
    const float* __restrict__ hbase = his_p + (size_t)b * NHIS * ND;

#pragma unroll
    for (int it = 0; it < 4; ++it) {
        const int task = it * 128 + grp;
        if (task < NCDD * NHIS) {
            const int c = task / NHIS, h = task - c * NHIS;
            const float* __restrict__ crow = cbase + (size_t)c * ND;
            const float* __restrict__ hrow = hbase + (size_t)h * ND;
            float a = 0.f;
#pragma unroll
            for (int i = 0; i < 16; ++i) {
                const int kb = sub * 4 + 16 * i;
                const float4 cv = *(const float4*)(crow + kb);
                const float4 hv = *(const float4*)(hrow + kb);
                a += cv.x * hv.x + cv.y * hv.y + cv.z * hv.z + cv.w * hv.w;
            }
            a += __shfl_xor(a, 1);
            a += __shfl_xor(a, 2);
            if (sub == 0) attn_s[c][h] = a;
        }
    }
    __syncthreads();

    if (wave < NCDD) {
        const int c = wave;
        float v0 = attn_s[c][lane];
        float v1 = (lane + 64 < NHIS) ? attn_s[c][lane + 64] : NEG_INF;
#pragma unroll
        for (int k = 0; k < NK; ++k) {
            float lv; int li;
            if (v1 > v0) { lv = v1; li = lane + 64; }
            else         { lv = v0; li = lane; }            // tie -> lower idx
            for (int off = 1; off < 64; off <<= 1) {
                const float ov = __shfl_xor(lv, off);
                const int   oi = __shfl_xor(li, off);
                if (ov > lv || (ov == lv && oi < li)) { lv = ov; li = oi; }
            }
            if (lane == 0) {
                const float w = (lv < THRESH) ? 0.0f : lv;
                const int g = (b * NCDD + c) * NK + k;
                ws_idx[g] = li;
                ws_w[g]   = w;
                out_idx_f[g] = (float)li;
            }
            if (li == lane)            v0 = NEG_INF;
            else if (li == lane + 64)  v1 = NEG_INF;
        }
    }
}

// ---------------------------------------------------------------------------
// Kernel 3: gather + scale, MAX-MLP restructure. Each thread owns 22 f32x4
// slots (threads 0..127 own a 23rd tail slot). ALL loads are issued before
// the first store — one waitcnt ladder, 22-23 loads in flight per lane
// (the R8 version stalled on an 8-deep load/store batch round-trip).
// ~92 VGPR data buffer -> still 16 waves/CU. Zero path unchanged.
// ---------------------------------------------------------------------------
__global__ __launch_bounds__(256) void gather_kernel(
    const float* __restrict__ his_emb,
    const int* __restrict__ ws_idx,
    const float* __restrict__ ws_w,
    float* __restrict__ out)
{
    const int orig = blockIdx.x;
    const int g = (orig & 7) * 400 + (orig >> 3);   // XCD-chunked (bijective)
    const int b = g / (NCDD * NK);
    const int tid = threadIdx.x;
    const float w = ws_w[g];

    f32x4* __restrict__ dst = (f32x4*)(out + (size_t)g * TLD);

    if (w == 0.0f) {
        const f32x4 z = {0.f, 0.f, 0.f, 0.f};
#pragma unroll
        for (int it = 0; it < 22; ++it) dst[tid + it * 256] = z;
        if (tid < 128) dst[22 * 256 + tid] = z;
        return;
    }

    const int idx = ws_idx[g];
    const f32x4* __restrict__ src =
        (const f32x4*)(his_emb + ((size_t)b * NHIS + idx) * TLD);

    f32x4 v[22];
    f32x4 vt;
#pragma unroll
    for (int j = 0; j < 22; ++j) v[j] = src[tid + j * 256];
    const bool tail = (tid < 128);
    if (tail) vt = src[22 * 256 + tid];

#pragma unroll
    for (int j = 0; j < 22; ++j) dst[tid + j * 256] = v[j] * w;
    if (tail) dst[22 * 256 + tid] = vt * w;
}

// ---------------------------------------------------------------------------
extern "C" void kernel_launch(void* const* d_in, const int* in_sizes, int n_in,
                              void* d_out, int out_size, void* d_ws, size_t ws_size,
                              hipStream_t stream)
{
    const float* cdd_repr = (const float*)d_in[0];   // (64,5,256)
    const float* his_repr = (const float*)d_in[1];   // (64,100,256)
    const float* his_emb  = (const float*)d_in[2];   // (64,100,30,3,256)
    const float* W_sel    = (const float*)d_in[3];   // (256,256)
    const float* b_sel    = (const float*)d_in[4];   // (256,)
    float* out = (float*)d_out;

    // Workspace layout
    char* ws = (char*)d_ws;
    float* Yall  = (float*)ws;                       // 6720 rows * 256 * 4
    float* his_p = Yall;                             // rows [0, 6400)
    float* cdd_p = Yall + (size_t)NROWS_HIS * ND;    // rows [6400, 6720)
    int*   idx_i = (int*)  (ws + 6881280);           // 3200*4
    float* w_w   = (float*)(ws + 6894080);           // 3200*4

    // Output: his_activated [73,728,000] then idx [3200] (as float values)
    float* out_idx_f = out + (size_t)NB * NCDD * NK * TLD;

    proj_norm_all<<<(NROWS_HIS + NROWS_CDD) / 8, 256, 0, stream>>>(
        his_repr, cdd_repr, W_sel, b_sel, Yall);
    attn_topk_kernel<<<NB, 512, 0, stream>>>(cdd_p, his_p,
                                             out_idx_f, idx_i, w_w);
    gather_kernel<<<NB * NCDD * NK, 256, 0, stream>>>(his_emb, idx_i, w_w, out);
}